// Round 1
// baseline (84.243 us; speedup 1.0000x reference)
//
#include <hip/hip_runtime.h>

#define MARGIN 0.2f
#define EPS_    1e-8f

// D = 512 floats per row -> 128 float4 -> 2 float4 per lane (wave=64).
// One wave handles one triplet per grid-stride iteration.
__global__ __launch_bounds__(256) void triplet_loss_kernel(
    const float* __restrict__ batch,
    const float* __restrict__ beta,
    const int*   __restrict__ labels,
    const int*   __restrict__ triplets,
    int T, int D,
    float*        __restrict__ ws_total,
    unsigned int* __restrict__ ws_cnt)
{
    const int lane   = threadIdx.x & 63;
    const int wid    = threadIdx.x >> 6;                         // wave-in-block
    const int gwave  = (blockIdx.x * blockDim.x + threadIdx.x) >> 6;
    const int nwaves = (gridDim.x * blockDim.x) >> 6;
    const int dq     = D >> 2;                                   // float4 count per row

    float        tot = 0.0f;
    unsigned int cnt = 0u;

    for (int t = gwave; t < T; t += nwaves) {
        const int t0 = triplets[3 * t + 0];
        const int t1 = triplets[3 * t + 1];
        const int t2 = triplets[3 * t + 2];

        const float4* A = (const float4*)(batch + (size_t)t0 * D);
        const float4* P = (const float4*)(batch + (size_t)t1 * D);
        const float4* N = (const float4*)(batch + (size_t)t2 * D);

        float sap = 0.0f, san = 0.0f;
        #pragma unroll 2
        for (int idx = lane; idx < dq; idx += 64) {
            const float4 av = A[idx];
            const float4 pv = P[idx];
            const float4 nv = N[idx];
            float dx, dy, dz, dw;
            dx = av.x - pv.x; dy = av.y - pv.y; dz = av.z - pv.z; dw = av.w - pv.w;
            sap += dx * dx + dy * dy + dz * dz + dw * dw;
            dx = av.x - nv.x; dy = av.y - nv.y; dz = av.z - nv.z; dw = av.w - nv.w;
            san += dx * dx + dy * dy + dz * dz + dw * dw;
        }

        // 64-lane butterfly reduce (all lanes end with the full sums)
        #pragma unroll
        for (int off = 1; off < 64; off <<= 1) {
            sap += __shfl_xor(sap, off, 64);
            san += __shfl_xor(san, off, 64);
        }

        if (lane == 0) {
            const float d_ap = sqrtf(sap + EPS_);
            const float d_an = sqrtf(san + EPS_);
            const float b    = beta[labels[t0]];
            const float pos  = fmaxf((d_ap - b) + MARGIN, 0.0f);
            const float neg  = fmaxf((b - d_an) + MARGIN, 0.0f);
            tot += pos + neg;
            cnt += ((pos > 0.0f) || (neg > 0.0f)) ? 1u : 0u;
        }
    }

    // block reduce: one partial per wave -> thread 0 -> one atomic pair per block
    __shared__ float        s_tot[4];
    __shared__ unsigned int s_cnt[4];
    if (lane == 0) { s_tot[wid] = tot; s_cnt[wid] = cnt; }
    __syncthreads();
    if (threadIdx.x == 0) {
        float        bt = 0.0f;
        unsigned int bc = 0u;
        const int nw = blockDim.x >> 6;
        for (int i = 0; i < nw; ++i) { bt += s_tot[i]; bc += s_cnt[i]; }
        atomicAdd(ws_total, bt);
        atomicAdd(ws_cnt, bc);
    }
}

__global__ void finalize_kernel(const float* __restrict__ ws_total,
                                const unsigned int* __restrict__ ws_cnt,
                                float* __restrict__ out)
{
    const float total = ws_total[0];
    const float pc    = (float)ws_cnt[0];
    out[0] = (pc > 0.0f) ? (total / fmaxf(pc, 1.0f)) : total;
}

extern "C" void kernel_launch(void* const* d_in, const int* in_sizes, int n_in,
                              void* d_out, int out_size, void* d_ws, size_t ws_size,
                              hipStream_t stream)
{
    const float* batch    = (const float*)d_in[0];
    const float* beta     = (const float*)d_in[1];
    const int*   labels   = (const int*)d_in[2];
    const int*   triplets = (const int*)d_in[3];

    const int B = in_sizes[2];            // 4096 labels
    const int D = in_sizes[0] / B;        // 512
    const int T = in_sizes[3] / 3;        // 65536 triplets

    float*        ws_total = (float*)d_ws;
    unsigned int* ws_cnt   = (unsigned int*)((char*)d_ws + sizeof(float));

    // zero the two accumulators every call (harness does not re-poison)
    hipMemsetAsync(d_ws, 0, 2 * sizeof(float), stream);

    const int block = 256;                        // 4 waves/block
    int grid = 2048;                              // 8 blocks/CU on 256 CUs
    const int waves_needed = T;                   // one wave per triplet
    const int max_grid = (waves_needed + 3) / 4;  // don't over-launch
    if (grid > max_grid) grid = max_grid;

    triplet_loss_kernel<<<grid, block, 0, stream>>>(
        batch, beta, labels, triplets, T, D, ws_total, ws_cnt);

    finalize_kernel<<<1, 1, 0, stream>>>(ws_total, ws_cnt, (float*)d_out);
}

// Round 2
// 79.331 us; speedup vs baseline: 1.0619x; 1.0619x over previous
//
#include <hip/hip_runtime.h>

#define MARGIN 0.2f
#define EPS_    1e-8f

// ---------------------------------------------------------------------------
// beta_row[i] = beta[labels[i]]  (removes one level of the dependent-load
// chain triplets -> labels -> beta from the hot kernel)
// ---------------------------------------------------------------------------
__global__ void beta_row_kernel(const float* __restrict__ beta,
                                const int*   __restrict__ labels,
                                float*       __restrict__ beta_row, int B)
{
    int i = blockIdx.x * blockDim.x + threadIdx.x;
    if (i < B) beta_row[i] = beta[labels[i]];
}

// ---------------------------------------------------------------------------
// Fast path, D == 512 (dq = 128 float4 = 4 per 32-lane half).
// Split wave: lanes 0-31 accumulate |a-p|^2, lanes 32-63 accumulate |a-n|^2.
// Depth-1 software pipeline: loads for triplet t+1 issued before the
// reduce of triplet t. 2x unrolled ping-pong, all register indices static.
// ---------------------------------------------------------------------------
struct TriCtx {
    const float4* A;
    const float4* PN;
    float b;
};

__device__ __forceinline__ TriCtx tri_setup(const float* __restrict__ batch,
                                            const float* __restrict__ brow,
                                            const int*   __restrict__ triplets,
                                            int t, int D, int half)
{
    int t0 = triplets[3 * t + 0];
    int t1 = triplets[3 * t + 1];
    int t2 = triplets[3 * t + 2];
    // t is wave-uniform -> indices are wave-uniform; hoist into SGPRs
    t0 = __builtin_amdgcn_readfirstlane(t0);
    t1 = __builtin_amdgcn_readfirstlane(t1);
    t2 = __builtin_amdgcn_readfirstlane(t2);
    TriCtx r;
    r.A  = (const float4*)(batch + (size_t)t0 * D);
    const int tpn = half ? t2 : t1;
    r.PN = (const float4*)(batch + (size_t)tpn * D);
    r.b  = brow[t0];
    return r;
}

__device__ __forceinline__ void tri_issue(const TriCtx& c, int l32,
                                          float4* va, float4* vq)
{
    #pragma unroll
    for (int k = 0; k < 4; ++k) {
        va[k] = c.A [l32 + 32 * k];
        vq[k] = c.PN[l32 + 32 * k];
    }
}

__device__ __forceinline__ void tri_tally(const float4* va, const float4* vq,
                                          float b, int lane,
                                          float& tot, unsigned int& cnt)
{
    float s = 0.0f;
    #pragma unroll
    for (int k = 0; k < 4; ++k) {
        const float dx = va[k].x - vq[k].x;
        const float dy = va[k].y - vq[k].y;
        const float dz = va[k].z - vq[k].z;
        const float dw = va[k].w - vq[k].w;
        s = fmaf(dx, dx, s);
        s = fmaf(dy, dy, s);
        s = fmaf(dz, dz, s);
        s = fmaf(dw, dw, s);
    }
    // butterfly within each 32-lane half (5 steps), then cross-half swap
    #pragma unroll
    for (int off = 1; off < 32; off <<= 1)
        s += __shfl_xor(s, off, 64);
    const float o = __shfl_xor(s, 32, 64);
    if (lane == 0) {
        const float d_ap = sqrtf(s + EPS_);   // lane0 is in the a-p half
        const float d_an = sqrtf(o + EPS_);
        const float pos  = fmaxf(d_ap - b + MARGIN, 0.0f);
        const float neg  = fmaxf(b - d_an + MARGIN, 0.0f);
        tot += pos + neg;
        cnt += ((pos > 0.0f) || (neg > 0.0f)) ? 1u : 0u;
    }
}

__global__ __launch_bounds__(256) void triplet_loss_d512(
    const float* __restrict__ batch,
    const float* __restrict__ brow,
    const int*   __restrict__ triplets,
    int T, int D,
    float*        __restrict__ ws_total,
    unsigned int* __restrict__ ws_cnt)
{
    const int lane   = threadIdx.x & 63;
    const int wid    = threadIdx.x >> 6;
    const int l32    = lane & 31;
    const int half   = lane >> 5;
    const int gwave  = (blockIdx.x * blockDim.x + threadIdx.x) >> 6;
    const int nwaves = (gridDim.x * blockDim.x) >> 6;

    float        tot = 0.0f;
    unsigned int cnt = 0u;

    int t = gwave;
    if (t < T) {
        TriCtx c0 = tri_setup(batch, brow, triplets, t, D, half);
        float4 A0[4], Q0[4];
        tri_issue(c0, l32, A0, Q0);
        for (;;) {
            const int  tb = t + nwaves;
            const bool vb = tb < T;
            TriCtx c1; float4 A1[4], Q1[4];
            if (vb) {
                c1 = tri_setup(batch, brow, triplets, tb, D, half);
                tri_issue(c1, l32, A1, Q1);          // prefetch t+1
            }
            tri_tally(A0, Q0, c0.b, lane, tot, cnt); // consume t
            if (!vb) break;
            const int  tc = tb + nwaves;
            const bool vc = tc < T;
            if (vc) {
                c0 = tri_setup(batch, brow, triplets, tc, D, half);
                tri_issue(c0, l32, A0, Q0);          // prefetch t+2
            }
            tri_tally(A1, Q1, c1.b, lane, tot, cnt); // consume t+1
            if (!vc) break;
            t = tc;
        }
    }

    __shared__ float        s_tot[4];
    __shared__ unsigned int s_cnt[4];
    if (lane == 0) { s_tot[wid] = tot; s_cnt[wid] = cnt; }
    __syncthreads();
    if (threadIdx.x == 0) {
        float        bt = 0.0f;
        unsigned int bc = 0u;
        const int nw = blockDim.x >> 6;
        for (int i = 0; i < nw; ++i) { bt += s_tot[i]; bc += s_cnt[i]; }
        atomicAdd(ws_total, bt);
        atomicAdd(ws_cnt, bc);
    }
}

// ---------------------------------------------------------------------------
// Generic fallback (any D % 4 == 0) — round-1 kernel, with beta_row.
// ---------------------------------------------------------------------------
__global__ __launch_bounds__(256) void triplet_loss_generic(
    const float* __restrict__ batch,
    const float* __restrict__ brow,
    const int*   __restrict__ triplets,
    int T, int D,
    float*        __restrict__ ws_total,
    unsigned int* __restrict__ ws_cnt)
{
    const int lane   = threadIdx.x & 63;
    const int wid    = threadIdx.x >> 6;
    const int gwave  = (blockIdx.x * blockDim.x + threadIdx.x) >> 6;
    const int nwaves = (gridDim.x * blockDim.x) >> 6;
    const int dq     = D >> 2;

    float        tot = 0.0f;
    unsigned int cnt = 0u;

    for (int t = gwave; t < T; t += nwaves) {
        const int t0 = triplets[3 * t + 0];
        const int t1 = triplets[3 * t + 1];
        const int t2 = triplets[3 * t + 2];
        const float4* A = (const float4*)(batch + (size_t)t0 * D);
        const float4* P = (const float4*)(batch + (size_t)t1 * D);
        const float4* N = (const float4*)(batch + (size_t)t2 * D);
        float sap = 0.0f, san = 0.0f;
        for (int idx = lane; idx < dq; idx += 64) {
            const float4 av = A[idx];
            const float4 pv = P[idx];
            const float4 nv = N[idx];
            float dx = av.x - pv.x, dy = av.y - pv.y, dz = av.z - pv.z, dw = av.w - pv.w;
            sap += dx * dx + dy * dy + dz * dz + dw * dw;
            dx = av.x - nv.x; dy = av.y - nv.y; dz = av.z - nv.z; dw = av.w - nv.w;
            san += dx * dx + dy * dy + dz * dz + dw * dw;
        }
        #pragma unroll
        for (int off = 1; off < 64; off <<= 1) {
            sap += __shfl_xor(sap, off, 64);
            san += __shfl_xor(san, off, 64);
        }
        if (lane == 0) {
            const float d_ap = sqrtf(sap + EPS_);
            const float d_an = sqrtf(san + EPS_);
            const float b    = brow[t0];
            const float pos  = fmaxf(d_ap - b + MARGIN, 0.0f);
            const float neg  = fmaxf(b - d_an + MARGIN, 0.0f);
            tot += pos + neg;
            cnt += ((pos > 0.0f) || (neg > 0.0f)) ? 1u : 0u;
        }
    }

    __shared__ float        s_tot[4];
    __shared__ unsigned int s_cnt[4];
    if (lane == 0) { s_tot[wid] = tot; s_cnt[wid] = cnt; }
    __syncthreads();
    if (threadIdx.x == 0) {
        float        bt = 0.0f;
        unsigned int bc = 0u;
        const int nw = blockDim.x >> 6;
        for (int i = 0; i < nw; ++i) { bt += s_tot[i]; bc += s_cnt[i]; }
        atomicAdd(ws_total, bt);
        atomicAdd(ws_cnt, bc);
    }
}

__global__ void finalize_kernel(const float* __restrict__ ws_total,
                                const unsigned int* __restrict__ ws_cnt,
                                float* __restrict__ out)
{
    const float total = ws_total[0];
    const float pc    = (float)ws_cnt[0];
    out[0] = (pc > 0.0f) ? (total / fmaxf(pc, 1.0f)) : total;
}

extern "C" void kernel_launch(void* const* d_in, const int* in_sizes, int n_in,
                              void* d_out, int out_size, void* d_ws, size_t ws_size,
                              hipStream_t stream)
{
    const float* batch    = (const float*)d_in[0];
    const float* beta     = (const float*)d_in[1];
    const int*   labels   = (const int*)d_in[2];
    const int*   triplets = (const int*)d_in[3];

    const int B = in_sizes[2];            // 4096
    const int D = in_sizes[0] / B;        // 512
    const int T = in_sizes[3] / 3;        // 65536

    float*        ws_total = (float*)d_ws;
    unsigned int* ws_cnt   = (unsigned int*)((char*)d_ws + sizeof(float));
    float*        beta_row = (float*)((char*)d_ws + 1024);

    // zero accumulators every call (harness does not re-poison between replays)
    hipMemsetAsync(d_ws, 0, 2 * sizeof(float), stream);

    // precompute beta_row
    beta_row_kernel<<<(B + 255) / 256, 256, 0, stream>>>(beta, labels, beta_row, B);

    const int block = 256;
    int grid = 2048;                              // 8 triplets per wave
    const int max_grid = (T + 3) / 4;
    if (grid > max_grid) grid = max_grid;

    if (D == 512) {
        triplet_loss_d512<<<grid, block, 0, stream>>>(
            batch, beta_row, triplets, T, D, ws_total, ws_cnt);
    } else {
        triplet_loss_generic<<<grid, block, 0, stream>>>(
            batch, beta_row, triplets, T, D, ws_total, ws_cnt);
    }

    finalize_kernel<<<1, 1, 0, stream>>>(ws_total, ws_cnt, (float*)d_out);
}